// Round 15
// baseline (524.960 us; speedup 1.0000x reference)
//
#include <hip/hip_runtime.h>
#include <hip/hip_bf16.h>
#include <math.h>

#define Nn 20480
#define Cc 128
#define Hh 8
#define Ll 4
#define NWw 320
#define BN 81920   // B*N

typedef short sv8 __attribute__((ext_vector_type(8)));
typedef __bf16 bfv8 __attribute__((ext_vector_type(8)));
typedef float f32x4 __attribute__((ext_vector_type(4)));

__device__ __forceinline__ f32x4 mfma16(sv8 a, sv8 b, f32x4 c) {
    return __builtin_amdgcn_mfma_f32_16x16x32_bf16(
        __builtin_bit_cast(bfv8, a), __builtin_bit_cast(bfv8, b), c, 0, 0, 0);
}
__device__ __forceinline__ ushort f2bf(float f) {
    uint u = __float_as_uint(f);
    u += 0x7fffu + ((u >> 16) & 1u);
    return (ushort)(u >> 16);
}
__device__ __forceinline__ float b2f(ushort u) {
    return __uint_as_float((uint)u << 16);
}
__device__ __forceinline__ uint pk2bf(float lo, float hi) {
    uint r;
    asm("v_cvt_pk_bf16_f32 %0, %1, %2" : "=v"(r) : "v"(lo), "v"(hi));
    return r;
}
// tanh-gelu, constants folded
__device__ __forceinline__ float cgelu(float x) {
    float u = x * fmaf(x * x, -0.1029402f, -2.3021399f);
    float e = __builtin_exp2f(u);
    return x * __builtin_amdgcn_rcpf(1.0f + e);
}

// ---------- stable counting sort of window_ids ----------
__global__ __launch_bounds__(64) void rank_kernel(const int* __restrict__ wid,
        int* __restrict__ lrank, int* __restrict__ hist) {
    __shared__ int keys[64];
    int c = blockIdx.x, lane = threadIdx.x;
    for (int j = lane; j < NWw; j += 64) hist[c * NWw + j] = 0;
    int i = c * 64 + lane;
    int w = wid[i];
    keys[lane] = w;
    __syncthreads();
    int rank = 0, total = 0;
    for (int j = 0; j < 64; ++j) {
        int kj = keys[j];
        total += (kj == w);
        rank += (j < lane && kj == w) ? 1 : 0;
    }
    lrank[i] = rank;
    if (rank == 0) hist[c * NWw + w] = total;
}
__global__ __launch_bounds__(64) void prefix_kernel(int* __restrict__ hist) {
    int w = blockIdx.x, lane = threadIdx.x;
    int running = 0;
    for (int it = 0; it < NWw / 64; ++it) {
        int c = it * 64 + lane;
        int v = hist[c * NWw + w];
        int orig = v;
        #pragma unroll
        for (int d = 1; d < 64; d <<= 1) {
            int tt = __shfl_up(v, d, 64);
            if (lane >= d) v += tt;
        }
        hist[c * NWw + w] = running + v - orig;
        running += __shfl(v, 63, 64);
    }
}
__global__ __launch_bounds__(64) void scatter_kernel(const int* __restrict__ wid,
        const int* __restrict__ lrank, const int* __restrict__ hist,
        int* __restrict__ sidx) {
    int c = blockIdx.x, lane = threadIdx.x;
    int i = c * 64 + lane;
    int w = wid[i];
    sidx[w * 64 + hist[c * NWw + w] + lrank[i]] = i;
}

// ---------- weight convert + transpose to bf16 [N][K] ----------
__global__ __launch_bounds__(256) void wconv_kernel(
    const float* __restrict__ Wqkv, const float* __restrict__ Wproj,
    const float* __restrict__ W1, const float* __restrict__ W2,
    ushort* __restrict__ wt) {
    int id = blockIdx.x * 256 + threadIdx.x;      // < 786432
    int l = id / 196608;
    int r = id % 196608;
    const float* src; int dst;
    if (r < 49152) { int n = r % 384, k = r / 384;
        src = Wqkv + l * 49152 + k * 384 + n; dst = l * 196608 + n * 128 + k; }
    else if (r < 65536) { int rr = r - 49152; int n = rr % 128, k = rr / 128;
        src = Wproj + l * 16384 + k * 128 + n; dst = l * 196608 + 49152 + n * 128 + k; }
    else if (r < 131072) { int rr = r - 65536; int n = rr % 512, k = rr / 512;
        src = W1 + l * 65536 + k * 512 + n; dst = l * 196608 + 65536 + n * 128 + k; }
    else { int rr = r - 131072; int n = rr % 128, k = rr / 128;
        src = W2 + l * 65536 + k * 128 + n; dst = l * 196608 + 131072 + n * 512 + k; }
    wt[dst] = f2bf(*src);
}

// ---------- fused attention block (R14, unchanged) ----------
template <int SRCF>
__global__ __launch_bounds__(256, 2) void attn_fused_kernel(
    const void* __restrict__ xsrc_, ushort* __restrict__ xdst,
    const ushort* __restrict__ wqkvT, const float* __restrict__ bqkv,
    const float* __restrict__ relb, const ushort* __restrict__ wprojT,
    const float* __restrict__ bproj, const float* __restrict__ g1,
    const float* __restrict__ be1, const int* __restrict__ sidx) {
    __shared__ __align__(16) ushort hl_[64][128];
    __shared__ __align__(16) ushort qkn[64][256];
    __shared__ __align__(16) ushort vT[128][76];
    __shared__ __align__(16) ushort pt[4][16][76];
    __shared__ int ridx[64];

    const float*  xf = (const float*)xsrc_;
    const ushort* xb = (const ushort*)xsrc_;

    int t = threadIdx.x;
    int wave = t >> 6, lane = t & 63;
    int lr = lane & 15, lg = lane >> 4;
    int wb = blockIdx.x;
    int bN = (wb / NWw) * Nn;
    int p0 = (wb % NWw) * 64;

    if (t < 64) ridx[t] = sidx[p0 + t];
    __syncthreads();

    // ---- phase 1: gather + LN1 -> hl_
    {
        int hl2 = lane & 31, hb = lane >> 5;
        float4 gg = *(const float4*)(g1 + hl2 * 4);
        float4 bb = *(const float4*)(be1 + hl2 * 4);
        #pragma unroll
        for (int it = 0; it < 8; ++it) {
            int row = it * 8 + wave * 2 + hb;
            int gi = bN + ridx[row];
            float4 v;
            if constexpr (SRCF) {
                v = *(const float4*)(xf + (size_t)gi * Cc + hl2 * 4);
            } else {
                ushort4 u = *(const ushort4*)(xb + (size_t)gi * Cc + hl2 * 4);
                v.x = b2f(u.x); v.y = b2f(u.y); v.z = b2f(u.z); v.w = b2f(u.w);
            }
            float s = v.x + v.y + v.z + v.w;
            s += __shfl_xor(s, 1, 64);  s += __shfl_xor(s, 2, 64);
            s += __shfl_xor(s, 4, 64);  s += __shfl_xor(s, 8, 64);
            s += __shfl_xor(s, 16, 64);
            float mu = s * 0.0078125f;
            float d0 = v.x - mu, d1 = v.y - mu, d2 = v.z - mu, d3 = v.w - mu;
            float q = d0 * d0 + d1 * d1 + d2 * d2 + d3 * d3;
            q += __shfl_xor(q, 1, 64);  q += __shfl_xor(q, 2, 64);
            q += __shfl_xor(q, 4, 64);  q += __shfl_xor(q, 8, 64);
            q += __shfl_xor(q, 16, 64);
            float rs = rsqrtf(q * 0.0078125f + 1e-5f);
            uint2 pk;
            pk.x = pk2bf(d0 * rs * gg.x + bb.x, d1 * rs * gg.y + bb.y);
            pk.y = pk2bf(d2 * rs * gg.z + bb.z, d3 * rs * gg.w + bb.w);
            *(uint2*)&hl_[row][(hl2 * 4) ^ ((row & 7) << 3)] = pk;
        }
    }
    __syncthreads();

    // ---- phase 2: QKV GEMM; q,k SWAPPED (packed LDS writes), v original
    {
        f32x4 accqk[4][4] = {};
        f32x4 accv[4][2]  = {};
        #pragma unroll
        for (int ks = 0; ks < 4; ++ks) {
            int k0 = ks * 32 + lg * 8;
            sv8 a[4], b[6];
            #pragma unroll
            for (int rf = 0; rf < 4; ++rf) {
                int row = rf * 16 + lr;
                a[rf] = *(const sv8*)&hl_[row][k0 ^ ((row & 7) << 3)];
            }
            #pragma unroll
            for (int nf = 0; nf < 6; ++nf) {
                int gcol = (nf < 2 ? 32 * wave + nf * 16
                          : nf < 4 ? 128 + 32 * wave + (nf - 2) * 16
                                   : 256 + 32 * wave + (nf - 4) * 16) + lr;
                b[nf] = *(const sv8*)(wqkvT + (size_t)gcol * 128 + k0);
            }
            #pragma unroll
            for (int nf = 0; nf < 4; ++nf)
                #pragma unroll
                for (int rf = 0; rf < 4; ++rf)
                    accqk[nf][rf] = mfma16(b[nf], a[rf], accqk[nf][rf]);
            #pragma unroll
            for (int rf = 0; rf < 4; ++rf)
                #pragma unroll
                for (int nf = 0; nf < 2; ++nf)
                    accv[rf][nf] = mfma16(a[rf], b[4 + nf], accv[rf][nf]);
        }
        #pragma unroll
        for (int nf = 0; nf < 4; ++nf) {
            int gcolb = (nf < 2 ? 32 * wave + nf * 16
                                : 128 + 32 * wave + (nf - 2) * 16) + lg * 4;
            float4 bs = *(const float4*)(bqkv + gcolb);
            #pragma unroll
            for (int rf = 0; rf < 4; ++rf) {
                int tok = rf * 16 + lr;
                uint2 pk;
                pk.x = pk2bf(accqk[nf][rf][0] + bs.x, accqk[nf][rf][1] + bs.y);
                pk.y = pk2bf(accqk[nf][rf][2] + bs.z, accqk[nf][rf][3] + bs.w);
                *(uint2*)&qkn[tok][gcolb ^ ((tok & 7) << 3)] = pk;
            }
        }
        #pragma unroll
        for (int nf = 0; nf < 2; ++nf) {
            int gcol = 256 + 32 * wave + nf * 16 + lr;
            float bs = bqkv[gcol];
            int dcol = gcol - 256;
            #pragma unroll
            for (int rf = 0; rf < 4; ++rf) {
                uint2 pk;
                pk.x = pk2bf(accv[rf][nf][0] + bs, accv[rf][nf][1] + bs);
                pk.y = pk2bf(accv[rf][nf][2] + bs, accv[rf][nf][3] + bs);
                *(uint2*)&vT[dcol][rf * 16 + lg * 4] = pk;
            }
        }
    }
    __syncthreads();

    // ---- phase 3: attention (swapped QK^T), 2 heads per wave; PV swapped
    f32x4 zz = {0.f, 0.f, 0.f, 0.f};
    #pragma unroll
    for (int hi = 0; hi < 2; ++hi) {
        int hh = wave * 2 + hi;
        float rb = relb[hh];
        sv8 bv[2];
        #pragma unroll
        for (int ks = 0; ks < 2; ++ks)
            bv[ks] = *(const sv8*)&vT[hh * 16 + lr][ks * 32 + lg * 8];
        sv8 aq[4], bk[4];
        sv8 z = {0, 0, 0, 0, 0, 0, 0, 0};
        bool lo = (lg < 2);
        #pragma unroll
        for (int f = 0; f < 4; ++f) {
            aq[f] = z; bk[f] = z;
            if (lo) {
                int row = f * 16 + lr;
                aq[f] = *(const sv8*)&qkn[row][(hh * 16 + lg * 8) ^ ((row & 7) << 3)];
                bk[f] = *(const sv8*)&qkn[row][(128 + hh * 16 + lg * 8) ^ ((row & 7) << 3)];
            }
        }
        f32x4 s[4][4];
        #pragma unroll
        for (int kt = 0; kt < 4; ++kt)
            #pragma unroll
            for (int qt = 0; qt < 4; ++qt)
                s[kt][qt] = mfma16(bk[kt], aq[qt], zz);

        f32x4 o[4];
        #pragma unroll
        for (int qt = 0; qt < 4; ++qt) {
            float v[16];
            #pragma unroll
            for (int kt = 0; kt < 4; ++kt)
                #pragma unroll
                for (int r = 0; r < 4; ++r)
                    v[kt * 4 + r] = s[kt][qt][r] * 0.25f + rb;
            float m0 = fmaxf(fmaxf(fmaxf(v[0], v[1]), fmaxf(v[2], v[3])),
                             fmaxf(fmaxf(v[4], v[5]), fmaxf(v[6], v[7])));
            float m1 = fmaxf(fmaxf(fmaxf(v[8], v[9]), fmaxf(v[10], v[11])),
                             fmaxf(fmaxf(v[12], v[13]), fmaxf(v[14], v[15])));
            float mx = fmaxf(m0, m1);
            mx = fmaxf(mx, __shfl_xor(mx, 16, 64));
            mx = fmaxf(mx, __shfl_xor(mx, 32, 64));
            float sum = 0.f;
            #pragma unroll
            for (int i = 0; i < 16; ++i) {
                v[i] = __expf(v[i] - mx);
                sum += v[i];
            }
            sum += __shfl_xor(sum, 16, 64);
            sum += __shfl_xor(sum, 32, 64);
            float inv = __builtin_amdgcn_rcpf(sum);
            #pragma unroll
            for (int kt = 0; kt < 4; ++kt) {
                uint2 pk;
                pk.x = pk2bf(v[kt * 4 + 0] * inv, v[kt * 4 + 1] * inv);
                pk.y = pk2bf(v[kt * 4 + 2] * inv, v[kt * 4 + 3] * inv);
                *(uint2*)&pt[wave][lr][kt * 16 + lg * 4] = pk;
            }
            sv8 ap0 = *(const sv8*)&pt[wave][lr][lg * 8];
            sv8 ap1 = *(const sv8*)&pt[wave][lr][32 + lg * 8];
            o[qt] = mfma16(bv[0], ap0, zz);
            o[qt] = mfma16(bv[1], ap1, o[qt]);
        }
        #pragma unroll
        for (int qt = 0; qt < 4; ++qt) {
            int tok = qt * 16 + lr;
            int d0 = hh * 16 + lg * 4;
            uint2 pk;
            pk.x = pk2bf(o[qt][0], o[qt][1]);
            pk.y = pk2bf(o[qt][2], o[qt][3]);
            *(uint2*)&hl_[tok][d0 ^ ((tok & 7) << 3)] = pk;
        }
    }
    __syncthreads();

    // ---- phase 4: proj SWAPPED + bias + residual -> bf16 x_mid
    {
        f32x4 accp[2][4] = {};
        #pragma unroll
        for (int ks = 0; ks < 4; ++ks) {
            int k0 = ks * 32 + lg * 8;
            sv8 a[4], b[2];
            #pragma unroll
            for (int rf = 0; rf < 4; ++rf) {
                int row = rf * 16 + lr;
                a[rf] = *(const sv8*)&hl_[row][k0 ^ ((row & 7) << 3)];
            }
            #pragma unroll
            for (int nf = 0; nf < 2; ++nf)
                b[nf] = *(const sv8*)(wprojT + (size_t)(wave * 32 + nf * 16 + lr) * 128 + k0);
            #pragma unroll
            for (int nf = 0; nf < 2; ++nf)
                #pragma unroll
                for (int rf = 0; rf < 4; ++rf)
                    accp[nf][rf] = mfma16(b[nf], a[rf], accp[nf][rf]);
        }
        #pragma unroll
        for (int nf = 0; nf < 2; ++nf) {
            int n0 = wave * 32 + nf * 16 + lg * 4;
            float4 bs = *(const float4*)(bproj + n0);
            #pragma unroll
            for (int rf = 0; rf < 4; ++rf) {
                int tok = rf * 16 + lr;
                int gi = bN + ridx[tok];
                size_t ad = (size_t)gi * Cc + n0;
                float r0_, r1_, r2_, r3_;
                if constexpr (SRCF) {
                    float4 rv = *(const float4*)(xf + ad);
                    r0_ = rv.x; r1_ = rv.y; r2_ = rv.z; r3_ = rv.w;
                } else {
                    ushort4 u = *(const ushort4*)(xb + ad);
                    r0_ = b2f(u.x); r1_ = b2f(u.y); r2_ = b2f(u.z); r3_ = b2f(u.w);
                }
                uint2 pk;
                pk.x = pk2bf(r0_ + accp[nf][rf][0] + bs.x, r1_ + accp[nf][rf][1] + bs.y);
                pk.y = pk2bf(r2_ + accp[nf][rf][2] + bs.z, r3_ + accp[nf][rf][3] + bs.w);
                *(uint2*)(xdst + ad) = pk;
            }
        }
    }
}

// ---------- fused MLP; R15: hid halved to 2 chunks of 256 -> LDS 48KB -> 3 blocks/CU ----------
// (256,2) kept: no VGPR squeeze. Full-ILP MLP1 halves (acc[4][4] swapped).
template <int DSTF>
__global__ __launch_bounds__(256, 2) void mlp_fused_kernel(
    const ushort* __restrict__ xs, void* __restrict__ xdst_,
    const ushort* __restrict__ w1T, const float* __restrict__ b1,
    const ushort* __restrict__ w2T, const float* __restrict__ b2,
    const float* __restrict__ g2, const float* __restrict__ be2) {
    __shared__ __align__(16) ushort hl_[64][128];   // 16 KB
    __shared__ __align__(16) ushort hid[64][256];   // 32 KB (one 256-col chunk)
    int t = threadIdx.x, wave = t >> 6, lane = t & 63;
    int lr = lane & 15, lg = lane >> 4;
    int r0 = blockIdx.x * 64;
    int xw = (lr & 7) << 3;

    // phase 1: LN2 (bf16 in)
    {
        int hl2 = lane & 31, hb = lane >> 5;
        float4 gg = *(const float4*)(g2 + hl2 * 4);
        float4 bb = *(const float4*)(be2 + hl2 * 4);
        #pragma unroll
        for (int it = 0; it < 8; ++it) {
            int row = it * 8 + wave * 2 + hb;
            ushort4 u = *(const ushort4*)(xs + (size_t)(r0 + row) * Cc + hl2 * 4);
            float4 v;
            v.x = b2f(u.x); v.y = b2f(u.y); v.z = b2f(u.z); v.w = b2f(u.w);
            float s = v.x + v.y + v.z + v.w;
            s += __shfl_xor(s, 1, 64);  s += __shfl_xor(s, 2, 64);
            s += __shfl_xor(s, 4, 64);  s += __shfl_xor(s, 8, 64);
            s += __shfl_xor(s, 16, 64);
            float mu = s * 0.0078125f;
            float d0 = v.x - mu, d1 = v.y - mu, d2 = v.z - mu, d3 = v.w - mu;
            float q = d0 * d0 + d1 * d1 + d2 * d2 + d3 * d3;
            q += __shfl_xor(q, 1, 64);  q += __shfl_xor(q, 2, 64);
            q += __shfl_xor(q, 4, 64);  q += __shfl_xor(q, 8, 64);
            q += __shfl_xor(q, 16, 64);
            float rs = rsqrtf(q * 0.0078125f + 1e-5f);
            uint2 pk;
            pk.x = pk2bf(d0 * rs * gg.x + bb.x, d1 * rs * gg.y + bb.y);
            pk.y = pk2bf(d2 * rs * gg.z + bb.z, d3 * rs * gg.w + bb.w);
            *(uint2*)&hl_[row][(hl2 * 4) ^ ((row & 7) << 3)] = pk;
        }
    }
    __syncthreads();

    // phases 2..3: two 256-col hidden chunks
    f32x4 acc2[4][2] = {};
    #pragma unroll
    for (int ch = 0; ch < 2; ++ch) {
        // MLP1 half (swapped): wave covers hidden cols [ch*256 + wave*64, +64)
        {
            f32x4 acc[4][4] = {};   // [nf][rf]
            #pragma unroll
            for (int ks = 0; ks < 4; ++ks) {
                int k0 = ks * 32 + lg * 8;
                sv8 a[4], b[4];
                #pragma unroll
                for (int rf = 0; rf < 4; ++rf) {
                    int row = rf * 16 + lr;
                    a[rf] = *(const sv8*)&hl_[row][k0 ^ ((row & 7) << 3)];
                }
                #pragma unroll
                for (int nf = 0; nf < 4; ++nf)
                    b[nf] = *(const sv8*)(w1T + (size_t)(ch * 256 + wave * 64 + nf * 16 + lr) * 128 + k0);
                #pragma unroll
                for (int nf = 0; nf < 4; ++nf)
                    #pragma unroll
                    for (int rf = 0; rf < 4; ++rf)
                        acc[nf][rf] = mfma16(b[nf], a[rf], acc[nf][rf]);
            }
            #pragma unroll
            for (int nf = 0; nf < 4; ++nf) {
                int nl = wave * 64 + nf * 16 + lg * 4;      // chunk-local col
                float4 bs = *(const float4*)(b1 + ch * 256 + nl);
                #pragma unroll
                for (int rf = 0; rf < 4; ++rf) {
                    int tok = rf * 16 + lr;
                    float g0 = cgelu(acc[nf][rf][0] + bs.x);
                    float g1 = cgelu(acc[nf][rf][1] + bs.y);
                    float g2v = cgelu(acc[nf][rf][2] + bs.z);
                    float g3 = cgelu(acc[nf][rf][3] + bs.w);
                    uint2 pk;
                    pk.x = pk2bf(g0, g1);
                    pk.y = pk2bf(g2v, g3);
                    *(uint2*)&hid[tok][nl ^ xw] = pk;
                }
            }
        }
        __syncthreads();   // hid chunk visible
        // MLP2 partial over this chunk (K=256, 8 ksteps)
        #pragma unroll
        for (int ks = 0; ks < 8; ++ks) {
            int k0 = ks * 32 + lg * 8;
            sv8 a[4], b[2];
            #pragma unroll
            for (int rf = 0; rf < 4; ++rf)
                a[rf] = *(const sv8*)&hid[rf * 16 + lr][k0 ^ xw];
            #pragma unroll
            for (int nf = 0; nf < 2; ++nf)
                b[nf] = *(const sv8*)(w2T + (size_t)(wave * 32 + nf * 16 + lr) * 512 + ch * 256 + k0);
            #pragma unroll
            for (int rf = 0; rf < 4; ++rf)
                #pragma unroll
                for (int nf = 0; nf < 2; ++nf)
                    acc2[rf][nf] = mfma16(a[rf], b[nf], acc2[rf][nf]);
        }
        if (ch == 0) __syncthreads();   // all reads done before chunk 1 overwrites hid
    }

    // epilogue: bias + residual, direct
    #pragma unroll
    for (int nf = 0; nf < 2; ++nf) {
        int col = wave * 32 + nf * 16 + lr;
        float bs = b2[col];
        #pragma unroll
        for (int rf = 0; rf < 4; ++rf)
            #pragma unroll
            for (int r = 0; r < 4; ++r) {
                int row = rf * 16 + lg * 4 + r;
                size_t ad = (size_t)(r0 + row) * Cc + col;
                float o = b2f(xs[ad]) + acc2[rf][nf][r] + bs;
                if constexpr (DSTF) ((float*)xdst_)[ad] = o;
                else ((ushort*)xdst_)[ad] = f2bf(o);
            }
    }
}

extern "C" void kernel_launch(void* const* d_in, const int* in_sizes, int n_in,
                              void* d_out, int out_size, void* d_ws, size_t ws_size,
                              hipStream_t stream) {
    const float* x_in   = (const float*)d_in[0];
    const float* g1     = (const float*)d_in[1];
    const float* be1    = (const float*)d_in[2];
    const float* Wqkv   = (const float*)d_in[3];
    const float* bqkv   = (const float*)d_in[4];
    const float* relb   = (const float*)d_in[5];
    const float* Wproj  = (const float*)d_in[6];
    const float* bproj  = (const float*)d_in[7];
    const float* g2     = (const float*)d_in[8];
    const float* be2    = (const float*)d_in[9];
    const float* W1     = (const float*)d_in[10];
    const float* b1     = (const float*)d_in[11];
    const float* W2     = (const float*)d_in[12];
    const float* b2     = (const float*)d_in[13];
    const int*   wid    = (const int*)d_in[14];

    size_t off = 0;
    ushort* x_mid = (ushort*)d_ws;                   off += (size_t)BN * Cc * 2;
    ushort* x_l   = (ushort*)((char*)d_ws + off);    off += (size_t)BN * Cc * 2;
    ushort* wt    = (ushort*)((char*)d_ws + off);    off += (size_t)786432 * 2;
    int* sidx     = (int*)((char*)d_ws + off);       off += (size_t)Nn * 4;
    int* lrank    = (int*)((char*)d_ws + off);       off += (size_t)Nn * 4;
    int* hist     = (int*)((char*)d_ws + off);       off += (size_t)NWw * NWw * 4;
    if (ws_size < off) return;

    rank_kernel<<<Nn / 64, 64, 0, stream>>>(wid, lrank, hist);
    prefix_kernel<<<NWw, 64, 0, stream>>>(hist);
    scatter_kernel<<<Nn / 64, 64, 0, stream>>>(wid, lrank, hist, sidx);
    wconv_kernel<<<786432 / 256, 256, 0, stream>>>(Wqkv, Wproj, W1, W2, wt);

    for (int l = 0; l < Ll; ++l) {
        const ushort* wqkvT  = wt + (size_t)l * 196608;
        const ushort* wprojT = wqkvT + 49152;
        const ushort* w1T    = wqkvT + 65536;
        const ushort* w2T    = wqkvT + 131072;

        if (l == 0)
            attn_fused_kernel<1><<<BN / 64, 256, 0, stream>>>(
                x_in, x_mid, wqkvT, bqkv + l * 384, relb + l * Hh,
                wprojT, bproj + l * Cc, g1 + l * Cc, be1 + l * Cc, sidx);
        else
            attn_fused_kernel<0><<<BN / 64, 256, 0, stream>>>(
                x_l, x_mid, wqkvT, bqkv + l * 384, relb + l * Hh,
                wprojT, bproj + l * Cc, g1 + l * Cc, be1 + l * Cc, sidx);

        if (l == Ll - 1)
            mlp_fused_kernel<1><<<BN / 64, 256, 0, stream>>>(
                x_mid, d_out, w1T, b1 + l * 512, w2T, b2 + l * Cc,
                g2 + l * Cc, be2 + l * Cc);
        else
            mlp_fused_kernel<0><<<BN / 64, 256, 0, stream>>>(
                x_mid, x_l, w1T, b1 + l * 512, w2T, b2 + l * Cc,
                g2 + l * Cc, be2 + l * Cc);
    }
}

// Round 16
// 432.939 us; speedup vs baseline: 1.2126x; 1.2126x over previous
//
#include <hip/hip_runtime.h>
#include <hip/hip_bf16.h>
#include <math.h>

#define Nn 20480
#define Cc 128
#define Hh 8
#define Ll 4
#define NWw 320
#define BN 81920   // B*N

typedef short sv8 __attribute__((ext_vector_type(8)));
typedef __bf16 bfv8 __attribute__((ext_vector_type(8)));
typedef float f32x4 __attribute__((ext_vector_type(4)));

__device__ __forceinline__ f32x4 mfma16(sv8 a, sv8 b, f32x4 c) {
    return __builtin_amdgcn_mfma_f32_16x16x32_bf16(
        __builtin_bit_cast(bfv8, a), __builtin_bit_cast(bfv8, b), c, 0, 0, 0);
}
__device__ __forceinline__ ushort f2bf(float f) {
    uint u = __float_as_uint(f);
    u += 0x7fffu + ((u >> 16) & 1u);
    return (ushort)(u >> 16);
}
__device__ __forceinline__ float b2f(ushort u) {
    return __uint_as_float((uint)u << 16);
}
__device__ __forceinline__ uint pk2bf(float lo, float hi) {
    uint r;
    asm("v_cvt_pk_bf16_f32 %0, %1, %2" : "=v"(r) : "v"(lo), "v"(hi));
    return r;
}
// tanh-gelu, constants folded
__device__ __forceinline__ float cgelu(float x) {
    float u = x * fmaf(x * x, -0.1029402f, -2.3021399f);
    float e = __builtin_exp2f(u);
    return x * __builtin_amdgcn_rcpf(1.0f + e);
}

// ---------- stable counting sort of window_ids ----------
__global__ __launch_bounds__(64) void rank_kernel(const int* __restrict__ wid,
        int* __restrict__ lrank, int* __restrict__ hist) {
    __shared__ int keys[64];
    int c = blockIdx.x, lane = threadIdx.x;
    for (int j = lane; j < NWw; j += 64) hist[c * NWw + j] = 0;
    int i = c * 64 + lane;
    int w = wid[i];
    keys[lane] = w;
    __syncthreads();
    int rank = 0, total = 0;
    for (int j = 0; j < 64; ++j) {
        int kj = keys[j];
        total += (kj == w);
        rank += (j < lane && kj == w) ? 1 : 0;
    }
    lrank[i] = rank;
    if (rank == 0) hist[c * NWw + w] = total;
}
__global__ __launch_bounds__(64) void prefix_kernel(int* __restrict__ hist) {
    int w = blockIdx.x, lane = threadIdx.x;
    int running = 0;
    for (int it = 0; it < NWw / 64; ++it) {
        int c = it * 64 + lane;
        int v = hist[c * NWw + w];
        int orig = v;
        #pragma unroll
        for (int d = 1; d < 64; d <<= 1) {
            int tt = __shfl_up(v, d, 64);
            if (lane >= d) v += tt;
        }
        hist[c * NWw + w] = running + v - orig;
        running += __shfl(v, 63, 64);
    }
}
__global__ __launch_bounds__(64) void scatter_kernel(const int* __restrict__ wid,
        const int* __restrict__ lrank, const int* __restrict__ hist,
        int* __restrict__ sidx) {
    int c = blockIdx.x, lane = threadIdx.x;
    int i = c * 64 + lane;
    int w = wid[i];
    sidx[w * 64 + hist[c * NWw + w] + lrank[i]] = i;
}

// ---------- weight convert + transpose to bf16 [N][K] ----------
__global__ __launch_bounds__(256) void wconv_kernel(
    const float* __restrict__ Wqkv, const float* __restrict__ Wproj,
    const float* __restrict__ W1, const float* __restrict__ W2,
    ushort* __restrict__ wt) {
    int id = blockIdx.x * 256 + threadIdx.x;      // < 786432
    int l = id / 196608;
    int r = id % 196608;
    const float* src; int dst;
    if (r < 49152) { int n = r % 384, k = r / 384;
        src = Wqkv + l * 49152 + k * 384 + n; dst = l * 196608 + n * 128 + k; }
    else if (r < 65536) { int rr = r - 49152; int n = rr % 128, k = rr / 128;
        src = Wproj + l * 16384 + k * 128 + n; dst = l * 196608 + 49152 + n * 128 + k; }
    else if (r < 131072) { int rr = r - 65536; int n = rr % 512, k = rr / 512;
        src = W1 + l * 65536 + k * 512 + n; dst = l * 196608 + 65536 + n * 128 + k; }
    else { int rr = r - 131072; int n = rr % 128, k = rr / 128;
        src = W2 + l * 65536 + k * 128 + n; dst = l * 196608 + 131072 + n * 512 + k; }
    wt[dst] = f2bf(*src);
}

// ---------- fused attention block; SRCF=1: xsrc fp32, else bf16. dst = bf16 x_mid ----------
// All epilogues packed via swapped-operand MFMA (q/k, PV, proj).
template <int SRCF>
__global__ __launch_bounds__(256, 2) void attn_fused_kernel(
    const void* __restrict__ xsrc_, ushort* __restrict__ xdst,
    const ushort* __restrict__ wqkvT, const float* __restrict__ bqkv,
    const float* __restrict__ relb, const ushort* __restrict__ wprojT,
    const float* __restrict__ bproj, const float* __restrict__ g1,
    const float* __restrict__ be1, const int* __restrict__ sidx) {
    __shared__ __align__(16) ushort hl_[64][128];
    __shared__ __align__(16) ushort qkn[64][256];
    __shared__ __align__(16) ushort vT[128][76];
    __shared__ __align__(16) ushort pt[4][16][76];
    __shared__ int ridx[64];

    const float*  xf = (const float*)xsrc_;
    const ushort* xb = (const ushort*)xsrc_;

    int t = threadIdx.x;
    int wave = t >> 6, lane = t & 63;
    int lr = lane & 15, lg = lane >> 4;
    int wb = blockIdx.x;
    int bN = (wb / NWw) * Nn;
    int p0 = (wb % NWw) * 64;

    if (t < 64) ridx[t] = sidx[p0 + t];
    __syncthreads();

    // ---- phase 1: gather + LN1 -> hl_
    {
        int hl2 = lane & 31, hb = lane >> 5;
        float4 gg = *(const float4*)(g1 + hl2 * 4);
        float4 bb = *(const float4*)(be1 + hl2 * 4);
        #pragma unroll
        for (int it = 0; it < 8; ++it) {
            int row = it * 8 + wave * 2 + hb;
            int gi = bN + ridx[row];
            float4 v;
            if constexpr (SRCF) {
                v = *(const float4*)(xf + (size_t)gi * Cc + hl2 * 4);
            } else {
                ushort4 u = *(const ushort4*)(xb + (size_t)gi * Cc + hl2 * 4);
                v.x = b2f(u.x); v.y = b2f(u.y); v.z = b2f(u.z); v.w = b2f(u.w);
            }
            float s = v.x + v.y + v.z + v.w;
            s += __shfl_xor(s, 1, 64);  s += __shfl_xor(s, 2, 64);
            s += __shfl_xor(s, 4, 64);  s += __shfl_xor(s, 8, 64);
            s += __shfl_xor(s, 16, 64);
            float mu = s * 0.0078125f;
            float d0 = v.x - mu, d1 = v.y - mu, d2 = v.z - mu, d3 = v.w - mu;
            float q = d0 * d0 + d1 * d1 + d2 * d2 + d3 * d3;
            q += __shfl_xor(q, 1, 64);  q += __shfl_xor(q, 2, 64);
            q += __shfl_xor(q, 4, 64);  q += __shfl_xor(q, 8, 64);
            q += __shfl_xor(q, 16, 64);
            float rs = rsqrtf(q * 0.0078125f + 1e-5f);
            uint2 pk;
            pk.x = pk2bf(d0 * rs * gg.x + bb.x, d1 * rs * gg.y + bb.y);
            pk.y = pk2bf(d2 * rs * gg.z + bb.z, d3 * rs * gg.w + bb.w);
            *(uint2*)&hl_[row][(hl2 * 4) ^ ((row & 7) << 3)] = pk;
        }
    }
    __syncthreads();

    // ---- phase 2: QKV GEMM; q,k SWAPPED (packed LDS writes), v original
    {
        f32x4 accqk[4][4] = {};   // [nf][rf]: mfma(w, h)
        f32x4 accv[4][2]  = {};   // [rf][nf-4]: mfma(h, w)
        #pragma unroll
        for (int ks = 0; ks < 4; ++ks) {
            int k0 = ks * 32 + lg * 8;
            sv8 a[4], b[6];
            #pragma unroll
            for (int rf = 0; rf < 4; ++rf) {
                int row = rf * 16 + lr;
                a[rf] = *(const sv8*)&hl_[row][k0 ^ ((row & 7) << 3)];
            }
            #pragma unroll
            for (int nf = 0; nf < 6; ++nf) {
                int gcol = (nf < 2 ? 32 * wave + nf * 16
                          : nf < 4 ? 128 + 32 * wave + (nf - 2) * 16
                                   : 256 + 32 * wave + (nf - 4) * 16) + lr;
                b[nf] = *(const sv8*)(wqkvT + (size_t)gcol * 128 + k0);
            }
            #pragma unroll
            for (int nf = 0; nf < 4; ++nf)
                #pragma unroll
                for (int rf = 0; rf < 4; ++rf)
                    accqk[nf][rf] = mfma16(b[nf], a[rf], accqk[nf][rf]);
            #pragma unroll
            for (int rf = 0; rf < 4; ++rf)
                #pragma unroll
                for (int nf = 0; nf < 2; ++nf)
                    accv[rf][nf] = mfma16(a[rf], b[4 + nf], accv[rf][nf]);
        }
        // q,k: lane holds 4 consecutive cols (gcolb..+3) of token rf*16+lr
        #pragma unroll
        for (int nf = 0; nf < 4; ++nf) {
            int gcolb = (nf < 2 ? 32 * wave + nf * 16
                                : 128 + 32 * wave + (nf - 2) * 16) + lg * 4;
            float4 bs = *(const float4*)(bqkv + gcolb);
            #pragma unroll
            for (int rf = 0; rf < 4; ++rf) {
                int tok = rf * 16 + lr;
                uint2 pk;
                pk.x = pk2bf(accqk[nf][rf][0] + bs.x, accqk[nf][rf][1] + bs.y);
                pk.y = pk2bf(accqk[nf][rf][2] + bs.z, accqk[nf][rf][3] + bs.w);
                *(uint2*)&qkn[tok][gcolb ^ ((tok & 7) << 3)] = pk;
            }
        }
        // v: original orientation -> vT[d][tok] packed rows of 4 tokens
        #pragma unroll
        for (int nf = 0; nf < 2; ++nf) {
            int gcol = 256 + 32 * wave + nf * 16 + lr;
            float bs = bqkv[gcol];
            int dcol = gcol - 256;
            #pragma unroll
            for (int rf = 0; rf < 4; ++rf) {
                uint2 pk;
                pk.x = pk2bf(accv[rf][nf][0] + bs, accv[rf][nf][1] + bs);
                pk.y = pk2bf(accv[rf][nf][2] + bs, accv[rf][nf][3] + bs);
                *(uint2*)&vT[dcol][rf * 16 + lg * 4] = pk;
            }
        }
    }
    __syncthreads();

    // ---- phase 3: attention (swapped QK^T), 2 heads per wave; PV swapped -> packed out
    f32x4 zz = {0.f, 0.f, 0.f, 0.f};
    #pragma unroll
    for (int hi = 0; hi < 2; ++hi) {
        int hh = wave * 2 + hi;
        float rb = relb[hh];
        sv8 bv[2];
        #pragma unroll
        for (int ks = 0; ks < 2; ++ks)
            bv[ks] = *(const sv8*)&vT[hh * 16 + lr][ks * 32 + lg * 8];
        sv8 aq[4], bk[4];
        sv8 z = {0, 0, 0, 0, 0, 0, 0, 0};
        bool lo = (lg < 2);
        #pragma unroll
        for (int f = 0; f < 4; ++f) {
            aq[f] = z; bk[f] = z;
            if (lo) {
                int row = f * 16 + lr;
                aq[f] = *(const sv8*)&qkn[row][(hh * 16 + lg * 8) ^ ((row & 7) << 3)];
                bk[f] = *(const sv8*)&qkn[row][(128 + hh * 16 + lg * 8) ^ ((row & 7) << 3)];
            }
        }
        f32x4 s[4][4];
        #pragma unroll
        for (int kt = 0; kt < 4; ++kt)
            #pragma unroll
            for (int qt = 0; qt < 4; ++qt)
                s[kt][qt] = mfma16(bk[kt], aq[qt], zz);

        f32x4 o[4];
        #pragma unroll
        for (int qt = 0; qt < 4; ++qt) {
            float v[16];
            #pragma unroll
            for (int kt = 0; kt < 4; ++kt)
                #pragma unroll
                for (int r = 0; r < 4; ++r)
                    v[kt * 4 + r] = s[kt][qt][r] * 0.25f + rb;
            float m0 = fmaxf(fmaxf(fmaxf(v[0], v[1]), fmaxf(v[2], v[3])),
                             fmaxf(fmaxf(v[4], v[5]), fmaxf(v[6], v[7])));
            float m1 = fmaxf(fmaxf(fmaxf(v[8], v[9]), fmaxf(v[10], v[11])),
                             fmaxf(fmaxf(v[12], v[13]), fmaxf(v[14], v[15])));
            float mx = fmaxf(m0, m1);
            mx = fmaxf(mx, __shfl_xor(mx, 16, 64));
            mx = fmaxf(mx, __shfl_xor(mx, 32, 64));
            float sum = 0.f;
            #pragma unroll
            for (int i = 0; i < 16; ++i) {
                v[i] = __expf(v[i] - mx);
                sum += v[i];
            }
            sum += __shfl_xor(sum, 16, 64);
            sum += __shfl_xor(sum, 32, 64);
            float inv = __builtin_amdgcn_rcpf(sum);
            #pragma unroll
            for (int kt = 0; kt < 4; ++kt) {
                uint2 pk;
                pk.x = pk2bf(v[kt * 4 + 0] * inv, v[kt * 4 + 1] * inv);
                pk.y = pk2bf(v[kt * 4 + 2] * inv, v[kt * 4 + 3] * inv);
                *(uint2*)&pt[wave][lr][kt * 16 + lg * 4] = pk;
            }
            sv8 ap0 = *(const sv8*)&pt[wave][lr][lg * 8];
            sv8 ap1 = *(const sv8*)&pt[wave][lr][32 + lg * 8];
            // swapped PV: D row = d (4 consecutive), col = q token
            o[qt] = mfma16(bv[0], ap0, zz);
            o[qt] = mfma16(bv[1], ap1, o[qt]);
        }
        #pragma unroll
        for (int qt = 0; qt < 4; ++qt) {
            int tok = qt * 16 + lr;
            int d0 = hh * 16 + lg * 4;
            uint2 pk;
            pk.x = pk2bf(o[qt][0], o[qt][1]);
            pk.y = pk2bf(o[qt][2], o[qt][3]);
            *(uint2*)&hl_[tok][d0 ^ ((tok & 7) << 3)] = pk;
        }
    }
    __syncthreads();

    // ---- phase 4: proj SWAPPED + bias + residual -> bf16 x_mid, packed ushort4 stores
    {
        f32x4 accp[2][4] = {};   // [nf][rf]: mfma(w, h)
        #pragma unroll
        for (int ks = 0; ks < 4; ++ks) {
            int k0 = ks * 32 + lg * 8;
            sv8 a[4], b[2];
            #pragma unroll
            for (int rf = 0; rf < 4; ++rf) {
                int row = rf * 16 + lr;
                a[rf] = *(const sv8*)&hl_[row][k0 ^ ((row & 7) << 3)];
            }
            #pragma unroll
            for (int nf = 0; nf < 2; ++nf)
                b[nf] = *(const sv8*)(wprojT + (size_t)(wave * 32 + nf * 16 + lr) * 128 + k0);
            #pragma unroll
            for (int nf = 0; nf < 2; ++nf)
                #pragma unroll
                for (int rf = 0; rf < 4; ++rf)
                    accp[nf][rf] = mfma16(b[nf], a[rf], accp[nf][rf]);
        }
        #pragma unroll
        for (int nf = 0; nf < 2; ++nf) {
            int n0 = wave * 32 + nf * 16 + lg * 4;
            float4 bs = *(const float4*)(bproj + n0);
            #pragma unroll
            for (int rf = 0; rf < 4; ++rf) {
                int tok = rf * 16 + lr;
                int gi = bN + ridx[tok];
                size_t ad = (size_t)gi * Cc + n0;
                float r0_, r1_, r2_, r3_;
                if constexpr (SRCF) {
                    float4 rv = *(const float4*)(xf + ad);
                    r0_ = rv.x; r1_ = rv.y; r2_ = rv.z; r3_ = rv.w;
                } else {
                    ushort4 u = *(const ushort4*)(xb + ad);
                    r0_ = b2f(u.x); r1_ = b2f(u.y); r2_ = b2f(u.z); r3_ = b2f(u.w);
                }
                uint2 pk;
                pk.x = pk2bf(r0_ + accp[nf][rf][0] + bs.x, r1_ + accp[nf][rf][1] + bs.y);
                pk.y = pk2bf(r2_ + accp[nf][rf][2] + bs.z, r3_ + accp[nf][rf][3] + bs.w);
                *(uint2*)(xdst + ad) = pk;
            }
        }
    }
}

// ---------- fused MLP block (R13 structure: hid[64][512], swapped MLP1, cgelu) ----------
template <int DSTF>
__global__ __launch_bounds__(256, 2) void mlp_fused_kernel(
    const ushort* __restrict__ xs, void* __restrict__ xdst_,
    const ushort* __restrict__ w1T, const float* __restrict__ b1,
    const ushort* __restrict__ w2T, const float* __restrict__ b2,
    const float* __restrict__ g2, const float* __restrict__ be2) {
    __shared__ __align__(16) ushort hl_[64][128];
    __shared__ __align__(16) ushort hid[64][512];
    int t = threadIdx.x, wave = t >> 6, lane = t & 63;
    int lr = lane & 15, lg = lane >> 4;
    int r0 = blockIdx.x * 64;
    int xw = (lr & 7) << 3;

    // phase 1: LN2 (bf16 in)
    {
        int hl2 = lane & 31, hb = lane >> 5;
        float4 gg = *(const float4*)(g2 + hl2 * 4);
        float4 bb = *(const float4*)(be2 + hl2 * 4);
        #pragma unroll
        for (int it = 0; it < 8; ++it) {
            int row = it * 8 + wave * 2 + hb;
            ushort4 u = *(const ushort4*)(xs + (size_t)(r0 + row) * Cc + hl2 * 4);
            float4 v;
            v.x = b2f(u.x); v.y = b2f(u.y); v.z = b2f(u.z); v.w = b2f(u.w);
            float s = v.x + v.y + v.z + v.w;
            s += __shfl_xor(s, 1, 64);  s += __shfl_xor(s, 2, 64);
            s += __shfl_xor(s, 4, 64);  s += __shfl_xor(s, 8, 64);
            s += __shfl_xor(s, 16, 64);
            float mu = s * 0.0078125f;
            float d0 = v.x - mu, d1 = v.y - mu, d2 = v.z - mu, d3 = v.w - mu;
            float q = d0 * d0 + d1 * d1 + d2 * d2 + d3 * d3;
            q += __shfl_xor(q, 1, 64);  q += __shfl_xor(q, 2, 64);
            q += __shfl_xor(q, 4, 64);  q += __shfl_xor(q, 8, 64);
            q += __shfl_xor(q, 16, 64);
            float rs = rsqrtf(q * 0.0078125f + 1e-5f);
            uint2 pk;
            pk.x = pk2bf(d0 * rs * gg.x + bb.x, d1 * rs * gg.y + bb.y);
            pk.y = pk2bf(d2 * rs * gg.z + bb.z, d3 * rs * gg.w + bb.w);
            *(uint2*)&hl_[row][(hl2 * 4) ^ ((row & 7) << 3)] = pk;
        }
    }
    __syncthreads();

    // phase 2: MLP1 (SWAPPED) + cheap gelu -> packed hid
    {
        f32x4 acc[8][4] = {};
        #pragma unroll
        for (int ks = 0; ks < 4; ++ks) {
            int k0 = ks * 32 + lg * 8;
            sv8 a[4], b[8];
            #pragma unroll
            for (int rf = 0; rf < 4; ++rf) {
                int row = rf * 16 + lr;
                a[rf] = *(const sv8*)&hl_[row][k0 ^ ((row & 7) << 3)];
            }
            #pragma unroll
            for (int nf = 0; nf < 8; ++nf)
                b[nf] = *(const sv8*)(w1T + (size_t)(wave * 128 + nf * 16 + lr) * 128 + k0);
            #pragma unroll
            for (int nf = 0; nf < 8; ++nf)
                #pragma unroll
                for (int rf = 0; rf < 4; ++rf)
                    acc[nf][rf] = mfma16(b[nf], a[rf], acc[nf][rf]);
        }
        #pragma unroll
        for (int nf = 0; nf < 8; ++nf) {
            int n0 = wave * 128 + nf * 16 + lg * 4;
            float4 bs = *(const float4*)(b1 + n0);
            #pragma unroll
            for (int rf = 0; rf < 4; ++rf) {
                int tok = rf * 16 + lr;
                float g0 = cgelu(acc[nf][rf][0] + bs.x);
                float g1 = cgelu(acc[nf][rf][1] + bs.y);
                float g2v = cgelu(acc[nf][rf][2] + bs.z);
                float g3 = cgelu(acc[nf][rf][3] + bs.w);
                uint2 pk;
                pk.x = pk2bf(g0, g1);
                pk.y = pk2bf(g2v, g3);
                *(uint2*)&hid[tok][n0 ^ xw] = pk;
            }
        }
    }
    __syncthreads();

    // phase 3: MLP2 (K=512) + bias + residual, direct epilogue
    {
        f32x4 acc2[4][2] = {};
        #pragma unroll
        for (int ks = 0; ks < 16; ++ks) {
            int k0 = ks * 32 + lg * 8;
            sv8 a[4], b[2];
            #pragma unroll
            for (int rf = 0; rf < 4; ++rf)
                a[rf] = *(const sv8*)&hid[rf * 16 + lr][k0 ^ xw];
            #pragma unroll
            for (int nf = 0; nf < 2; ++nf)
                b[nf] = *(const sv8*)(w2T + (size_t)(wave * 32 + nf * 16 + lr) * 512 + k0);
            #pragma unroll
            for (int rf = 0; rf < 4; ++rf)
                #pragma unroll
                for (int nf = 0; nf < 2; ++nf)
                    acc2[rf][nf] = mfma16(a[rf], b[nf], acc2[rf][nf]);
        }
        #pragma unroll
        for (int nf = 0; nf < 2; ++nf) {
            int col = wave * 32 + nf * 16 + lr;
            float bs = b2[col];
            #pragma unroll
            for (int rf = 0; rf < 4; ++rf)
                #pragma unroll
                for (int r = 0; r < 4; ++r) {
                    int row = rf * 16 + lg * 4 + r;
                    size_t ad = (size_t)(r0 + row) * Cc + col;
                    float o = b2f(xs[ad]) + acc2[rf][nf][r] + bs;
                    if constexpr (DSTF) ((float*)xdst_)[ad] = o;
                    else ((ushort*)xdst_)[ad] = f2bf(o);
                }
        }
    }
}

extern "C" void kernel_launch(void* const* d_in, const int* in_sizes, int n_in,
                              void* d_out, int out_size, void* d_ws, size_t ws_size,
                              hipStream_t stream) {
    const float* x_in   = (const float*)d_in[0];
    const float* g1     = (const float*)d_in[1];
    const float* be1    = (const float*)d_in[2];
    const float* Wqkv   = (const float*)d_in[3];
    const float* bqkv   = (const float*)d_in[4];
    const float* relb   = (const float*)d_in[5];
    const float* Wproj  = (const float*)d_in[6];
    const float* bproj  = (const float*)d_in[7];
    const float* g2     = (const float*)d_in[8];
    const float* be2    = (const float*)d_in[9];
    const float* W1     = (const float*)d_in[10];
    const float* b1     = (const float*)d_in[11];
    const float* W2     = (const float*)d_in[12];
    const float* b2     = (const float*)d_in[13];
    const int*   wid    = (const int*)d_in[14];

    size_t off = 0;
    ushort* x_mid = (ushort*)d_ws;                   off += (size_t)BN * Cc * 2;
    ushort* x_l   = (ushort*)((char*)d_ws + off);    off += (size_t)BN * Cc * 2;
    ushort* wt    = (ushort*)((char*)d_ws + off);    off += (size_t)786432 * 2;
    int* sidx     = (int*)((char*)d_ws + off);       off += (size_t)Nn * 4;
    int* lrank    = (int*)((char*)d_ws + off);       off += (size_t)Nn * 4;
    int* hist     = (int*)((char*)d_ws + off);       off += (size_t)NWw * NWw * 4;
    if (ws_size < off) return;

    rank_kernel<<<Nn / 64, 64, 0, stream>>>(wid, lrank, hist);
    prefix_kernel<<<NWw, 64, 0, stream>>>(hist);
    scatter_kernel<<<Nn / 64, 64, 0, stream>>>(wid, lrank, hist, sidx);
    wconv_kernel<<<786432 / 256, 256, 0, stream>>>(Wqkv, Wproj, W1, W2, wt);

    for (int l = 0; l < Ll; ++l) {
        const ushort* wqkvT  = wt + (size_t)l * 196608;
        const ushort* wprojT = wqkvT + 49152;
        const ushort* w1T    = wqkvT + 65536;
        const ushort* w2T    = wqkvT + 131072;

        if (l == 0)
            attn_fused_kernel<1><<<BN / 64, 256, 0, stream>>>(
                x_in, x_mid, wqkvT, bqkv + l * 384, relb + l * Hh,
                wprojT, bproj + l * Cc, g1 + l * Cc, be1 + l * Cc, sidx);
        else
            attn_fused_kernel<0><<<BN / 64, 256, 0, stream>>>(
                x_l, x_mid, wqkvT, bqkv + l * 384, relb + l * Hh,
                wprojT, bproj + l * Cc, g1 + l * Cc, be1 + l * Cc, sidx);

        if (l == Ll - 1)
            mlp_fused_kernel<1><<<BN / 64, 256, 0, stream>>>(
                x_mid, d_out, w1T, b1 + l * 512, w2T, b2 + l * Cc,
                g2 + l * Cc, be2 + l * Cc);
        else
            mlp_fused_kernel<0><<<BN / 64, 256, 0, stream>>>(
                x_mid, x_l, w1T, b1 + l * 512, w2T, b2 + l * Cc,
                g2 + l * Cc, be2 + l * Cc);
    }
}